// Round 7
// baseline (210.867 us; speedup 1.0000x reference)
//
#include <hip/hip_runtime.h>

// SpanRepresentation R5 (2nd resubmit after broker timeouts): contiguous-window writer.
// Output (8, 4068, 1556) f32 = 12,659,616 float4, flat. Block i owns the
// contiguous window [i*3112, (i+1)*3112) float4 (= 8 output rows, ~50 KB),
// swept in 13 block-wide 4 KB contiguous stores (fill-like stream).
// Source per float4 decoded arithmetically; x gathered through L2 (12.6 MB,
// re-read 16x), wemb L1-hot.

typedef float f4 __attribute__((ext_vector_type(4)));

#define ROW4    389          // 1556 f32 / 4
#define S_TOT   4068
#define WIN4    (8 * ROW4)   // 3112 float4 per block window
#define NBLK    4068         // 32544 rows / 8
#define NITER   13           // ceil(3112/256); last iter: threads 0..39

__global__ __launch_bounds__(256) void span_rep_win(
    const f4* __restrict__ x,
    const f4* __restrict__ we,
    f4* __restrict__ out)
{
    const int base = blockIdx.x * WIN4;

    #pragma unroll
    for (int i = 0; i < NITER; ++i) {
        const int local = i * 256 + (int)threadIdx.x;
        if (i == NITER - 1 && local >= WIN4) continue;
        const int idx = base + local;

        // decode: output row + column
        const unsigned row = (unsigned)idx / 389u;     // magic mul
        const int col = idx - (int)(row * 389u);       // 0..388
        const unsigned b = row / (unsigned)S_TOT;      // 0..7
        const int s = (int)row - (int)(b * S_TOT);     // span index

        // width-group decode: cumulative starts {0,512,1023,1533,2042,2550,3057,3563}
        int w = 1, cw = 0;
        if (s >= 512)  { w = 2; cw = 512;  }
        if (s >= 1023) { w = 3; cw = 1023; }
        if (s >= 1533) { w = 4; cw = 1533; }
        if (s >= 2042) { w = 5; cw = 2042; }
        if (s >= 2550) { w = 6; cw = 2550; }
        if (s >= 3057) { w = 7; cw = 3057; }
        if (s >= 3563) { w = 8; cw = 3563; }
        const int start = s - cw;

        // branchless source address select
        const int r = (col < 192) ? start : (start + w - 1);
        const int c = (col < 192) ? col : (col - 192);
        const int xoff = ((int)b * 512 + r) * 192 + c;
        const int bucket = (int)((0x765543210ull >> (4 * w)) & 0xF);
        const int woff = bucket * 5 + (col - 384);
        const f4* src = (col < 384) ? (x + xoff) : (we + woff);

        out[idx] = *src;
    }
}

extern "C" void kernel_launch(void* const* d_in, const int* in_sizes, int n_in,
                              void* d_out, int out_size, void* d_ws, size_t ws_size,
                              hipStream_t stream) {
    const f4* x  = (const f4*)d_in[0];  // (8, 512, 768) f32
    const f4* we = (const f4*)d_in[1];  // (14, 20) f32
    f4* out = (f4*)d_out;               // (8, 4068, 1556) f32 flat

    span_rep_win<<<NBLK, 256, 0, stream>>>(x, we, out);
}